// Round 1
// baseline (183.975 us; speedup 1.0000x reference)
//
#include <hip/hip_runtime.h>

#define B_DIM   2048
#define IN_DIM  4096
#define OUT_DIM 4096
#define FAN     64

// R6: 8-row cells + ds_read_b128 gathers + 1024-thread blocks @ 128 KB LDS.
//  Phase 1: pack fp32 -> bf16 8-ROW cells in d_ws. Tile t = rows 8t..8t+7
//    (256 tiles), cell (t,c) = 16 B at wsp[t*4096 + c]:
//    dw0 = bf16 rows(0,1), dw1 = rows(2,3), dw2 = rows(4,5), dw3 = rows(6,7).
//  Phase 2: grid 64 bsegs x 4 oblocks = 256 blocks (exactly 1/CU), 1024 threads
//    = 16 waves/CU (vs R5's 8). 128 KB static LDS = TWO 64 KB tile buffers,
//    double-buffered via global_load_lds width=16. Gather: one ds_read_b128
//    per (o, f, 8 rows) -> half the LDS wave-ops of R5 and coarser bank bins
//    (8 quad-groups vs 16 pairs) -> lower conflict multiplier.
//    Inner: ds_read_b128 -> 4x v_pk_fma_f32.

typedef float v2f __attribute__((ext_vector_type(2)));

__device__ __forceinline__ unsigned bf16_rne(float f) {
    unsigned u = __float_as_uint(f);
    return (u + 0x7fffu + ((u >> 16) & 1u)) >> 16;   // round-to-nearest-even bf16
}

// ---------------- Phase 1: pack fp32 -> bf16 8-row cells ----------------
__global__ __launch_bounds__(256) void pack_kernel(
    const float* __restrict__ input, uint4* __restrict__ wsp)
{
    const int idx = blockIdx.x * 256 + threadIdx.x;   // [0, 524288) cell-pairs
    const int t   = idx >> 11;                        // tile [0,256)
    const int c0  = (idx & 2047) << 1;                // column pair base

    const float* p = input + (size_t)t * 8 * IN_DIM + c0;
    float2 r[8];
    #pragma unroll
    for (int i = 0; i < 8; ++i)
        r[i] = *reinterpret_cast<const float2*>(p + i * IN_DIM);

    uint4 q0, q1;                                     // cells c0 and c0+1
    q0.x = bf16_rne(r[0].x) | (bf16_rne(r[1].x) << 16);
    q0.y = bf16_rne(r[2].x) | (bf16_rne(r[3].x) << 16);
    q0.z = bf16_rne(r[4].x) | (bf16_rne(r[5].x) << 16);
    q0.w = bf16_rne(r[6].x) | (bf16_rne(r[7].x) << 16);
    q1.x = bf16_rne(r[0].y) | (bf16_rne(r[1].y) << 16);
    q1.y = bf16_rne(r[2].y) | (bf16_rne(r[3].y) << 16);
    q1.z = bf16_rne(r[4].y) | (bf16_rne(r[5].y) << 16);
    q1.w = bf16_rne(r[6].y) | (bf16_rne(r[7].y) << 16);

    wsp[(size_t)t * 4096 + c0 + 0] = q0;
    wsp[(size_t)t * 4096 + c0 + 1] = q1;
}

// ---------------- Phase 2: pipelined gather + accumulate ----------------
__global__ __launch_bounds__(1024, 4) void condensed_kernel(
    const uint4* __restrict__ wsp,
    const float* __restrict__ weight,
    const float* __restrict__ bias,
    const int*   __restrict__ mask,
    float*       __restrict__ out)
{
    __shared__ __align__(16) uint4 lds[8192];         // 128 KB = 2 x 4096 uint4

    const int tid     = threadIdx.x;
    const int o       = blockIdx.y * 1024 + tid;
    const int tbase   = blockIdx.x * 4;               // 4 tiles of 8 rows
    const int rowbase = blockIdx.x * 32;              // 32 batch rows per block

    // ---- idx -> LDS byte addresses (cell = 16 B) + weights, in registers ----
    unsigned addrs[FAN];
    float    wv[FAN];
    {
        const int4*   mv = reinterpret_cast<const int4*>(mask)     + o * (FAN / 4);
        const float4* wp = reinterpret_cast<const float4*>(weight) + o * (FAN / 4);
        #pragma unroll
        for (int j = 0; j < FAN / 4; ++j) {
            int4   m4 = mv[j];
            float4 w4 = wp[j];
            addrs[4*j+0] = (unsigned)m4.x << 4;
            addrs[4*j+1] = (unsigned)m4.y << 4;
            addrs[4*j+2] = (unsigned)m4.z << 4;
            addrs[4*j+3] = (unsigned)m4.w << 4;
            wv[4*j+0] = w4.x;
            wv[4*j+1] = w4.y;
            wv[4*j+2] = w4.z;
            wv[4*j+3] = w4.w;
        }
    }
    const float bv = bias[o];

    // ---- prologue: DMA tile 0 -> buf0 (64 KB, 4 x 16 B per thread) ----
    {
        const uint4* src = wsp + (size_t)tbase * 4096 + tid;
        #pragma unroll
        for (int it = 0; it < 4; ++it) {
            __builtin_amdgcn_global_load_lds(
                (const __attribute__((address_space(1))) unsigned*)(src + it * 1024),
                (__attribute__((address_space(3))) unsigned*)(lds + it * 1024 + tid),
                16, 0, 0);
        }
    }
    __syncthreads();

    const char* ldsb = reinterpret_cast<const char*>(lds);

    #pragma unroll
    for (int p = 0; p < 4; ++p) {
        // prefetch next tile into the spare buffer (overlaps with gather below)
        if (p < 3) {
            const uint4* src = wsp + (size_t)(tbase + p + 1) * 4096 + tid;
            const int bufo = ((p + 1) & 1) * 4096;
            #pragma unroll
            for (int it = 0; it < 4; ++it) {
                __builtin_amdgcn_global_load_lds(
                    (const __attribute__((address_space(1))) unsigned*)(src + it * 1024),
                    (__attribute__((address_space(3))) unsigned*)(lds + bufo + it * 1024 + tid),
                    16, 0, 0);
            }
        }

        // gather + accumulate 8 rows from buf (p & 1)
        {
            const char* base = ldsb + (p & 1) * 65536;
            v2f a01 = {0.f, 0.f}, a23 = {0.f, 0.f}, a45 = {0.f, 0.f}, a67 = {0.f, 0.f};
            #pragma unroll
            for (int j = 0; j < FAN; ++j) {
                const uint4 g = *reinterpret_cast<const uint4*>(base + addrs[j]);
                const v2f w2 = {wv[j], wv[j]};
                v2f v;
                v.x = __uint_as_float(g.x << 16);
                v.y = __uint_as_float(g.x & 0xffff0000u);
                a01 = __builtin_elementwise_fma(v, w2, a01);
                v.x = __uint_as_float(g.y << 16);
                v.y = __uint_as_float(g.y & 0xffff0000u);
                a23 = __builtin_elementwise_fma(v, w2, a23);
                v.x = __uint_as_float(g.z << 16);
                v.y = __uint_as_float(g.z & 0xffff0000u);
                a45 = __builtin_elementwise_fma(v, w2, a45);
                v.x = __uint_as_float(g.w << 16);
                v.y = __uint_as_float(g.w & 0xffff0000u);
                a67 = __builtin_elementwise_fma(v, w2, a67);
            }

            float* op = out + (size_t)(rowbase + 8 * p) * OUT_DIM + o;
            op[0 * OUT_DIM] = a01.x + bv;
            op[1 * OUT_DIM] = a01.y + bv;
            op[2 * OUT_DIM] = a23.x + bv;
            op[3 * OUT_DIM] = a23.y + bv;
            op[4 * OUT_DIM] = a45.x + bv;
            op[5 * OUT_DIM] = a45.y + bv;
            op[6 * OUT_DIM] = a67.x + bv;
            op[7 * OUT_DIM] = a67.y + bv;
        }

        if (p < 3) __syncthreads();   // buf(p&1) free; prefetch DMA drained
    }
}

extern "C" void kernel_launch(void* const* d_in, const int* in_sizes, int n_in,
                              void* d_out, int out_size, void* d_ws, size_t ws_size,
                              hipStream_t stream) {
    const float* input  = (const float*)d_in[0];
    const float* weight = (const float*)d_in[1];
    const float* bias   = (const float*)d_in[2];
    const int*   mask   = (const int*)d_in[3];
    float*       out    = (float*)d_out;
    uint4*       wsp    = (uint4*)d_ws;               // needs 16 MiB

    pack_kernel<<<2048, 256, 0, stream>>>(input, wsp);
    dim3 grid(64, 4);   // 64 bsegs x 4 oblocks = 256 blocks = 1/CU (128 KB LDS)
    condensed_kernel<<<grid, 1024, 0, stream>>>(wsp, weight, bias, mask, out);
}